// Round 11
// baseline (466.774 us; speedup 1.0000x reference)
//
#include <hip/hip_runtime.h>
#include <hip/hip_bf16.h>
#include <stdint.h>

// Shapes (fixed by the problem)
#define BATCH 2048
#define NHID  512
#define KMAIN 65792          // 257*256  (k = i*256 + j, j<256; i=0..256)
#define NSTEP_ALL 1033       // 1028 main steps + 5 tail steps (j=256 column)
#define AW 320               // a_tab row width (257 vals: a[256]=1.0; zeros to 320)
#define CW 256               // c_tab row width
#define IPS 43               // i-values per split (6 splits cover i=0..256)

typedef __attribute__((ext_vector_type(8))) short short8;
typedef __attribute__((ext_vector_type(4))) short short4v;
typedef __attribute__((ext_vector_type(4))) float f32x4;

#define AS1 __attribute__((address_space(1)))
#define AS3 __attribute__((address_space(3)))

__device__ __forceinline__ unsigned short f2bf(float f) {
    union { float f; unsigned int u; } v; v.f = f;
    unsigned int r = v.u + 0x7FFFu + ((v.u >> 16) & 1u);
    return (unsigned short)(r >> 16);
}
__device__ __forceinline__ float bf2f(unsigned short u) {
    union { unsigned int i; float f; } v; v.i = ((unsigned int)u) << 16;
    return v.f;
}
__device__ __forceinline__ f32x4 MFMA16(short8 a, short8 b, f32x4 c) {
    return __builtin_amdgcn_mfma_f32_16x16x32_bf16(a, b, c, 0, 0, 0);
}

// W1 source row for permuted k (or -1 for zero-pad)
__device__ __forceinline__ int w1_src_row(int k) {
    if (k < KMAIN) return (k >> 8) * 257 + (k & 255);   // i*257 + j
    int i = k - KMAIN;
    return (i < 257) ? (i * 257 + 256) : -1;             // (i, j=256) column
}

// ---------------------------------------------------------------------------
// Merged prep: W1f (FRAGMENT-MAJOR permuted W1), W2t (row-major transpose),
// a_tab [2048][320] bf16, c_tab [2048][256] bf16.  One launch.
// W1f layout: chunk(n16, st, kk, lane) at ((n16*1033+st)*2+kk)*512 + lane*8,
// elems e: value = W1perm[st*64 + kk*32 + (lane>>4)*8 + e][n16*16 + (lane&15)].
// ---------------------------------------------------------------------------
__global__ __launch_bounds__(256) void prep_kernel(
        const float* __restrict__ inp1, const float* __restrict__ inp2,
        const float* __restrict__ W1, const float* __restrict__ W2,
        unsigned short* __restrict__ W1f, unsigned short* __restrict__ W2t,
        unsigned short* __restrict__ a_tab, unsigned short* __restrict__ c_tab) {
    __shared__ float T[64][65];
    int b = blockIdx.x;
    int t = threadIdx.x;

    if (b < 8264) {
        // ---- W1f tile: 64 k x 64 n ----
        int kt = b % 1033, nt = b / 1033;
        int k0 = kt * 64, n0 = nt * 64;
        int nn = t & 63, kk0 = t >> 6;
#pragma unroll
        for (int it = 0; it < 16; ++it) {
            int kk = it * 4 + kk0;
            int row = w1_src_row(k0 + kk);
            T[kk][nn] = (row >= 0) ? W1[(long)row * NHID + n0 + nn] : 0.f;
        }
        __syncthreads();
#pragma unroll
        for (int it = 0; it < 2; ++it) {
            int id = it * 256 + t;
            int n16l = id >> 7;            // 0..3
            int kk   = (id >> 6) & 1;
            int lw   = id & 63;
            short8 o;
#pragma unroll
            for (int e = 0; e < 8; ++e)
                o[e] = (short)f2bf(T[kk * 32 + (lw >> 4) * 8 + e][n16l * 16 + (lw & 15)]);
            size_t off = ((size_t)(((n0 >> 4) + n16l) * NSTEP_ALL + kt) * 2 + kk) * 512
                         + (size_t)lw * 8;
            *reinterpret_cast<short8*>(&W1f[off]) = o;
        }
    } else if (b < 8264 + 64) {
        // ---- W2t: plain transpose+cvt (row-major, gemm2's LDS path) ----
        int bb = b - 8264;
        int kt = bb & 7, nt = bb >> 3;
        int k0 = kt * 64, n0 = nt * 64;
        int nn = t & 63, kk0 = t >> 6;
#pragma unroll
        for (int it = 0; it < 16; ++it) {
            int kk = it * 4 + kk0;
            T[kk][nn] = W2[(long)(k0 + kk) * NHID + n0 + nn];
        }
        __syncthreads();
#pragma unroll
        for (int it = 0; it < 2; ++it) {
            int idx = it * 256 + t;
            int nl = idx >> 3, ch = idx & 7;
            short8 o;
#pragma unroll
            for (int e = 0; e < 8; ++e) o[e] = (short)f2bf(T[ch * 8 + e][nl]);
            *reinterpret_cast<short8*>(&W2t[(long)(n0 + nl) * NHID + k0 + ch * 8]) = o;
        }
    } else {
        int r0 = (b - 8328) * 32;
        for (int idx = t; idx < 32 * (AW / 8); idx += 256) {
            int r = idx / 40, ch = idx - r * 40;
            int m = r0 + r;
            short8 o;
#pragma unroll
            for (int e = 0; e < 8; ++e) {
                int i = ch * 8 + e;
                float v = (i < 256) ? inp1[m * 256 + i] : (i == 256 ? 1.0f : 0.0f);
                o[e] = (short)f2bf(v);
            }
            *reinterpret_cast<short8*>(&a_tab[m * AW + ch * 8]) = o;
        }
        for (int idx = t; idx < 32 * (CW / 8); idx += 256) {
            int r = idx >> 5, ch = idx & 31;
            int m = r0 + r;
            short8 o;
#pragma unroll
            for (int e = 0; e < 8; ++e) o[e] = (short)f2bf(inp2[m * 256 + ch * 8 + e]);
            *reinterpret_cast<short8*>(&c_tab[m * CW + ch * 8]) = o;
        }
    }
}

// ---------------------------------------------------------------------------
// Staging helpers (gemm2)
// ---------------------------------------------------------------------------
__device__ __forceinline__ void stage_tile128(const unsigned short* __restrict__ g,
        long row0, long k0, long ld, unsigned short* lds) {
    int t = threadIdx.x;
    int wave = t >> 6, lane = t & 63;
    int rl = lane >> 3;
    int ch = (lane & 7) ^ rl;
    const unsigned short* src0 = g + (row0 + wave * 8 + rl) * ld + k0 + ch * 8;
#pragma unroll
    for (int r = 0; r < 4; ++r) {
        const unsigned short* src = src0 + (long)r * 32 * ld;
        unsigned short* dst = lds + (r * 32 + wave * 8) * 64;
        __builtin_amdgcn_global_load_lds((const AS1 unsigned int*)src,
                                         (AS3 unsigned int*)dst, 16, 0, 0);
    }
}
// Fused h-staging: lds tile = bf16(relu(hacc + b1)), swizzled like stage_tile128
__device__ __forceinline__ void stage_h_tile(const float* __restrict__ hacc,
        const float* __restrict__ b1, int row0, int k0, unsigned short* lds) {
    int t = threadIdx.x;
    int wave = t >> 6, lane = t & 63;
    int rl = lane >> 3;
    int ch = lane & 7;
    int swch = ch ^ rl;
    f32x4 b0 = *(const f32x4*)(b1 + k0 + ch * 8);
    f32x4 b4 = *(const f32x4*)(b1 + k0 + ch * 8 + 4);
#pragma unroll
    for (int r = 0; r < 4; ++r) {
        int row = r * 32 + wave * 8 + rl;
        const float* src = hacc + (size_t)(row0 + row) * NHID + k0 + ch * 8;
        f32x4 v0 = *(const f32x4*)src;
        f32x4 v4 = *(const f32x4*)(src + 4);
        short8 o;
#pragma unroll
        for (int e = 0; e < 4; ++e) o[e]     = (short)f2bf(fmaxf(v0[e] + b0[e], 0.f));
#pragma unroll
        for (int e = 0; e < 4; ++e) o[4 + e] = (short)f2bf(fmaxf(v4[e] + b4[e], 0.f));
        *reinterpret_cast<short8*>(&lds[row * 64 + swch * 8]) = o;
    }
}
__device__ __forceinline__ short8 read_frag(const unsigned short* lds,
        int rowbase, int kofs, int lane) {
    int row = rowbase + (lane & 15);
    int chunkL = (kofs >> 3) + (lane >> 4);
    int sw = chunkL ^ (row & 7);
    return *reinterpret_cast<const short8*>(&lds[row * 64 + sw * 8]);
}

// ---------------------------------------------------------------------------
// GEMM1, BARRIER-FREE (see R10): each wave owns 64 rows x 32 cols; B frags
// streamed from fragment-major W1f (4 coalesced dwordx4/step, register
// double-buffered); A = raw register-cached c-chunks; fold per i-group with
// f32 a[output-row] from an LDS window.
// NOW 6 i-range splits (43/43/43/43/43/42+tail) -> grid 768 = 3 blocks/CU,
// 12 waves/CU: overlap deficit between MFMA and L2 loads was R10's limit.
// XCD grouping: 96 = 0 mod 8 -> all 8 mb-blocks of a (nt,s) group share XCD.
// ---------------------------------------------------------------------------
__global__ __launch_bounds__(256, 3) void gemm1_kernel(
        const unsigned short* __restrict__ a_tab,
        const unsigned short* __restrict__ c_tab,
        const unsigned short* __restrict__ W1f, float* __restrict__ hacc) {
    __shared__ __align__(16) unsigned short a_win[IPS * 256];  // [i][row] 22 KB

    int mb = blockIdx.x / 96;          // 0..7: 256-row slab
    int g96 = blockIdx.x % 96;
    int nt = g96 / 6;                  // 32-col slice
    int s  = g96 % 6;                  // i-range split
    int i0 = s * IPS;
    int ngroups = (s == 5) ? 42 : IPS; // i=215..256 for s=5
    int st0 = i0 * 4;

    int lane = threadIdx.x & 63;
    int wv   = threadIdx.x >> 6;
    int rowbase = mb * 256 + wv * 64;
    int frow = lane & 15;
    int kq = (lane >> 4) * 8;
    int r4 = (lane >> 4) * 4;
    int n16a = nt * 2, n16b = nt * 2 + 1;

    // per-lane c-chunk cache: cc[fm][q] = c_tab[rowbase+fm*16+frow][kq+32q ..+8)
    short8 cc[4][8];
#pragma unroll
    for (int fm = 0; fm < 4; ++fm)
#pragma unroll
        for (int q = 0; q < 8; ++q)
            cc[fm][q] = *reinterpret_cast<const short8*>(
                &c_tab[(size_t)(rowbase + fm * 16 + frow) * CW + kq + q * 32]);

    // a-window: a_win[i][row] = a_tab[mb*256+row][i0+i]
    {
        const unsigned short* src = a_tab + (size_t)(mb * 256 + threadIdx.x) * AW + i0;
        for (int i = 0; i < ngroups; ++i) a_win[i * 256 + threadIdx.x] = src[i];
    }
    __syncthreads();                   // the ONLY barrier

    f32x4 acc[4][2];
#pragma unroll
    for (int a = 0; a < 4; ++a)
#pragma unroll
        for (int b2 = 0; b2 < 2; ++b2) acc[a][b2] = (f32x4){0.f, 0.f, 0.f, 0.f};

    short8 bufE0, bufE1, bufE2, bufE3, bufO0, bufO1, bufO2, bufO3;

#define LOADSTEP(st, D) do { \
    const unsigned short* _p0 = W1f + ((size_t)(n16a * NSTEP_ALL + (st))) * 1024 + lane * 8; \
    const unsigned short* _p1 = W1f + ((size_t)(n16b * NSTEP_ALL + (st))) * 1024 + lane * 8; \
    D##0 = *reinterpret_cast<const short8*>(_p0); \
    D##1 = *reinterpret_cast<const short8*>(_p0 + 512); \
    D##2 = *reinterpret_cast<const short8*>(_p1); \
    D##3 = *reinterpret_cast<const short8*>(_p1 + 512); \
} while (0)
#define MFSTEP(B, p) do { \
    _Pragma("unroll") \
    for (int fm = 0; fm < 4; ++fm) { \
        P[fm][0] = MFMA16(cc[fm][2 * (p)],     B##0, P[fm][0]); \
        P[fm][1] = MFMA16(cc[fm][2 * (p)],     B##2, P[fm][1]); \
        P[fm][0] = MFMA16(cc[fm][2 * (p) + 1], B##1, P[fm][0]); \
        P[fm][1] = MFMA16(cc[fm][2 * (p) + 1], B##3, P[fm][1]); \
    } \
} while (0)

    LOADSTEP(st0, bufE);               // prologue

    for (int g = 0; g < ngroups; ++g) {
        int stg = st0 + g * 4;
        f32x4 P[4][2];
#pragma unroll
        for (int a = 0; a < 4; ++a)
#pragma unroll
            for (int b2 = 0; b2 < 2; ++b2) P[a][b2] = (f32x4){0.f, 0.f, 0.f, 0.f};

        LOADSTEP(stg + 1, bufO);  MFSTEP(bufE, 0);
        LOADSTEP(stg + 2, bufE);  MFSTEP(bufO, 1);
        LOADSTEP(stg + 3, bufO);  MFSTEP(bufE, 2);
        LOADSTEP(stg + 4, bufE);  MFSTEP(bufO, 3);   // max 1028 < 1033, in-bounds

        // fold i-group with a[OUTPUT row, i] in f32 (C/D rows are r4-based)
#pragma unroll
        for (int fm = 0; fm < 4; ++fm) {
            short4v a4 = *reinterpret_cast<const short4v*>(
                &a_win[g * 256 + wv * 64 + fm * 16 + r4]);
#pragma unroll
            for (int r = 0; r < 4; ++r) {
                float av = bf2f((unsigned short)a4[r]);
                acc[fm][0][r] += av * P[fm][0][r];
                acc[fm][1][r] += av * P[fm][1][r];
            }
        }
    }

    // tail (s==5): steps 1028..1032, fusion col = a(m,i); bufE holds 1028
    if (s == 5) {
#define TAILMF(B, p) do { \
    _Pragma("unroll") \
    for (int fm = 0; fm < 4; ++fm) { \
        const unsigned short* _ar = a_tab + (size_t)(rowbase + fm * 16 + frow) * AW + (p) * 64 + kq; \
        short8 t0 = *reinterpret_cast<const short8*>(_ar); \
        short8 t1 = *reinterpret_cast<const short8*>(_ar + 32); \
        acc[fm][0] = MFMA16(t0, B##0, acc[fm][0]); \
        acc[fm][1] = MFMA16(t0, B##2, acc[fm][1]); \
        acc[fm][0] = MFMA16(t1, B##1, acc[fm][0]); \
        acc[fm][1] = MFMA16(t1, B##3, acc[fm][1]); \
    } \
} while (0)
        LOADSTEP(1029, bufO);  TAILMF(bufE, 0);
        LOADSTEP(1030, bufE);  TAILMF(bufO, 1);
        LOADSTEP(1031, bufO);  TAILMF(bufE, 2);
        LOADSTEP(1032, bufE);  TAILMF(bufO, 3);
        TAILMF(bufE, 4);
    }

    // epilogue: atomic split-K accumulate into f32 hacc (in d_ws)
#pragma unroll
    for (int fm = 0; fm < 4; ++fm)
#pragma unroll
        for (int fn = 0; fn < 2; ++fn)
#pragma unroll
            for (int r = 0; r < 4; ++r) {
                int row = rowbase + fm * 16 + r4 + r;
                int col = nt * 32 + fn * 16 + frow;
                atomicAdd(&hacc[row * NHID + col], acc[fm][fn][r]);
            }
}

// ---------------------------------------------------------------------------
// GEMM2 (bias+relu+cvt fused into A-staging):
//   out = relu( bf16(relu(hacc + b1)) @ W2 + b2 ).  grid 16x4.
// ---------------------------------------------------------------------------
__global__ __launch_bounds__(256) void gemm2_kernel(
        const float* __restrict__ hacc, const float* __restrict__ b1,
        const unsigned short* __restrict__ W2t,
        const float* __restrict__ b2, float* __restrict__ out) {
    __shared__ unsigned short A_s[128 * 64];
    __shared__ unsigned short B_s[128 * 64];
    int m0 = (blockIdx.x >> 2) * 128;
    int n0 = (blockIdx.x & 3) * 128;
    int lane = threadIdx.x & 63;
    int wv = threadIdx.x >> 6;
    int wm = (wv >> 1) * 64;
    int wn = (wv & 1) * 64;

    f32x4 acc[4][4];
#pragma unroll
    for (int a = 0; a < 4; ++a)
#pragma unroll
        for (int b = 0; b < 4; ++b) acc[a][b] = (f32x4){0.f, 0.f, 0.f, 0.f};

    for (int st = 0; st < 8; ++st) {
        int kbase = st * 64;
        __syncthreads();
        stage_tile128(W2t, n0, kbase, NHID, B_s);   // async loads in flight...
        stage_h_tile(hacc, b1, m0, kbase, A_s);     // ...VALU staging overlaps
        __syncthreads();
#pragma unroll
        for (int kk = 0; kk < 2; ++kk) {
            short8 aF[4], bF[4];
#pragma unroll
            for (int fm = 0; fm < 4; ++fm) aF[fm] = read_frag(A_s, wm + fm * 16, kk * 32, lane);
#pragma unroll
            for (int fn = 0; fn < 4; ++fn) bF[fn] = read_frag(B_s, wn + fn * 16, kk * 32, lane);
#pragma unroll
            for (int fm = 0; fm < 4; ++fm)
#pragma unroll
                for (int fn = 0; fn < 4; ++fn)
                    acc[fm][fn] = __builtin_amdgcn_mfma_f32_16x16x32_bf16(
                        aF[fm], bF[fn], acc[fm][fn], 0, 0, 0);
        }
    }
    int cl = lane & 15;
    int r4 = (lane >> 4) * 4;
#pragma unroll
    for (int fm = 0; fm < 4; ++fm)
#pragma unroll
        for (int fn = 0; fn < 4; ++fn)
#pragma unroll
            for (int r = 0; r < 4; ++r) {
                int row = m0 + wm + fm * 16 + r4 + r;
                int col = n0 + wn + fn * 16 + cl;
                float x = acc[fm][fn][r] + b2[col];
                out[row * NHID + col] = fmaxf(x, 0.f);
            }
}

extern "C" void kernel_launch(void* const* d_in, const int* in_sizes, int n_in,
                              void* d_out, int out_size, void* d_ws, size_t ws_size,
                              hipStream_t stream) {
    const float* inp1 = (const float*)d_in[0];
    const float* inp2 = (const float*)d_in[1];
    const float* W1   = (const float*)d_in[2];
    const float* b1   = (const float*)d_in[3];
    const float* W2   = (const float*)d_in[4];
    const float* b2   = (const float*)d_in[5];
    float* out = (float*)d_out;

    // workspace layout (~75 MB)
    size_t off = 0;
    auto alloc = [&](size_t bytes) {
        void* p = (char*)d_ws + off;
        off += (bytes + 255) & ~(size_t)255;
        return p;
    };
    unsigned short* W1f   = (unsigned short*)alloc((size_t)32 * NSTEP_ALL * 1024 * 2);
    unsigned short* W2t   = (unsigned short*)alloc((size_t)NHID * NHID * 2);
    float*          hacc  = (float*)alloc((size_t)BATCH * NHID * 4);
    unsigned short* a_tab = (unsigned short*)alloc((size_t)BATCH * AW * 2);
    unsigned short* c_tab = (unsigned short*)alloc((size_t)BATCH * CW * 2);
    (void)ws_size; (void)in_sizes; (void)n_in; (void)out_size;

    hipMemsetAsync(hacc, 0, (size_t)BATCH * NHID * 4, stream);

    prep_kernel<<<8264 + 64 + 64, 256, 0, stream>>>(inp1, inp2, W1, W2,
                                                    W1f, W2t, a_tab, c_tab);

    gemm1_kernel<<<768, 256, 0, stream>>>(a_tab, c_tab, W1f, hacc);
    gemm2_kernel<<<64, 256, 0, stream>>>(hacc, b1, W2t, b2, out);
}

// Round 12
// 183.615 us; speedup vs baseline: 2.5421x; 2.5421x over previous
//
#include <hip/hip_runtime.h>
#include <hip/hip_bf16.h>
#include <stdint.h>

// Shapes (fixed by the problem)
#define BATCH 2048
#define NHID  512
#define KMAIN 65792          // 257*256  (k = i*256 + j, j<256; i=0..256)
#define NSTEP_ALL 1033       // 1028 main steps + 5 tail steps (j=256 column)
#define AW 320               // a_tab row width (257 vals: a[256]=1.0; zeros to 320)
#define CW 256               // c_tab row width

typedef __attribute__((ext_vector_type(8))) short short8;
typedef __attribute__((ext_vector_type(4))) short short4v;
typedef __attribute__((ext_vector_type(4))) float f32x4;

#define AS1 __attribute__((address_space(1)))
#define AS3 __attribute__((address_space(3)))

__device__ __forceinline__ unsigned short f2bf(float f) {
    union { float f; unsigned int u; } v; v.f = f;
    unsigned int r = v.u + 0x7FFFu + ((v.u >> 16) & 1u);
    return (unsigned short)(r >> 16);
}
__device__ __forceinline__ float bf2f(unsigned short u) {
    union { unsigned int i; float f; } v; v.i = ((unsigned int)u) << 16;
    return v.f;
}
__device__ __forceinline__ f32x4 MFMA16(short8 a, short8 b, f32x4 c) {
    return __builtin_amdgcn_mfma_f32_16x16x32_bf16(a, b, c, 0, 0, 0);
}

// W1 source row for permuted k (or -1 for zero-pad)
__device__ __forceinline__ int w1_src_row(int k) {
    if (k < KMAIN) return (k >> 8) * 257 + (k & 255);   // i*257 + j
    int i = k - KMAIN;
    return (i < 257) ? (i * 257 + 256) : -1;             // (i, j=256) column
}

// ---------------------------------------------------------------------------
// Merged prep: W1f (FRAGMENT-MAJOR permuted W1), W2t (row-major transpose),
// a_tab [2048][320] bf16, c_tab [2048][256] bf16.  One launch.
// W1f layout: chunk(n16, st, kk, lane) at ((n16*1033+st)*2+kk)*512 + lane*8,
// elems e: value = W1perm[st*64 + kk*32 + (lane>>4)*8 + e][n16*16 + (lane&15)].
// ---------------------------------------------------------------------------
__global__ __launch_bounds__(256) void prep_kernel(
        const float* __restrict__ inp1, const float* __restrict__ inp2,
        const float* __restrict__ W1, const float* __restrict__ W2,
        unsigned short* __restrict__ W1f, unsigned short* __restrict__ W2t,
        unsigned short* __restrict__ a_tab, unsigned short* __restrict__ c_tab) {
    __shared__ float T[64][65];
    int b = blockIdx.x;
    int t = threadIdx.x;

    if (b < 8264) {
        // ---- W1f tile: 64 k x 64 n ----
        int kt = b % 1033, nt = b / 1033;
        int k0 = kt * 64, n0 = nt * 64;
        int nn = t & 63, kk0 = t >> 6;
#pragma unroll
        for (int it = 0; it < 16; ++it) {
            int kk = it * 4 + kk0;
            int row = w1_src_row(k0 + kk);
            T[kk][nn] = (row >= 0) ? W1[(long)row * NHID + n0 + nn] : 0.f;
        }
        __syncthreads();
#pragma unroll
        for (int it = 0; it < 2; ++it) {
            int id = it * 256 + t;
            int n16l = id >> 7;            // 0..3
            int kk   = (id >> 6) & 1;
            int lw   = id & 63;
            short8 o;
#pragma unroll
            for (int e = 0; e < 8; ++e)
                o[e] = (short)f2bf(T[kk * 32 + (lw >> 4) * 8 + e][n16l * 16 + (lw & 15)]);
            size_t off = ((size_t)(((n0 >> 4) + n16l) * NSTEP_ALL + kt) * 2 + kk) * 512
                         + (size_t)lw * 8;
            *reinterpret_cast<short8*>(&W1f[off]) = o;
        }
    } else if (b < 8264 + 64) {
        // ---- W2t: plain transpose+cvt (row-major, gemm2's LDS path) ----
        int bb = b - 8264;
        int kt = bb & 7, nt = bb >> 3;
        int k0 = kt * 64, n0 = nt * 64;
        int nn = t & 63, kk0 = t >> 6;
#pragma unroll
        for (int it = 0; it < 16; ++it) {
            int kk = it * 4 + kk0;
            T[kk][nn] = W2[(long)(k0 + kk) * NHID + n0 + nn];
        }
        __syncthreads();
#pragma unroll
        for (int it = 0; it < 2; ++it) {
            int idx = it * 256 + t;
            int nl = idx >> 3, ch = idx & 7;
            short8 o;
#pragma unroll
            for (int e = 0; e < 8; ++e) o[e] = (short)f2bf(T[ch * 8 + e][nl]);
            *reinterpret_cast<short8*>(&W2t[(long)(n0 + nl) * NHID + k0 + ch * 8]) = o;
        }
    } else {
        int r0 = (b - 8328) * 32;
        for (int idx = t; idx < 32 * (AW / 8); idx += 256) {
            int r = idx / 40, ch = idx - r * 40;
            int m = r0 + r;
            short8 o;
#pragma unroll
            for (int e = 0; e < 8; ++e) {
                int i = ch * 8 + e;
                float v = (i < 256) ? inp1[m * 256 + i] : (i == 256 ? 1.0f : 0.0f);
                o[e] = (short)f2bf(v);
            }
            *reinterpret_cast<short8*>(&a_tab[m * AW + ch * 8]) = o;
        }
        for (int idx = t; idx < 32 * (CW / 8); idx += 256) {
            int r = idx >> 5, ch = idx & 31;
            int m = r0 + r;
            short8 o;
#pragma unroll
            for (int e = 0; e < 8; ++e) o[e] = (short)f2bf(inp2[m * 256 + ch * 8 + e]);
            *reinterpret_cast<short8*>(&c_tab[m * CW + ch * 8]) = o;
        }
    }
}

// ---------------------------------------------------------------------------
// Staging helpers (gemm2)
// ---------------------------------------------------------------------------
__device__ __forceinline__ void stage_tile128(const unsigned short* __restrict__ g,
        long row0, long k0, long ld, unsigned short* lds) {
    int t = threadIdx.x;
    int wave = t >> 6, lane = t & 63;
    int rl = lane >> 3;
    int ch = (lane & 7) ^ rl;
    const unsigned short* src0 = g + (row0 + wave * 8 + rl) * ld + k0 + ch * 8;
#pragma unroll
    for (int r = 0; r < 4; ++r) {
        const unsigned short* src = src0 + (long)r * 32 * ld;
        unsigned short* dst = lds + (r * 32 + wave * 8) * 64;
        __builtin_amdgcn_global_load_lds((const AS1 unsigned int*)src,
                                         (AS3 unsigned int*)dst, 16, 0, 0);
    }
}
// Fused h-staging: lds tile = bf16(relu(hacc + b1)), swizzled like stage_tile128
__device__ __forceinline__ void stage_h_tile(const float* __restrict__ hacc,
        const float* __restrict__ b1, int row0, int k0, unsigned short* lds) {
    int t = threadIdx.x;
    int wave = t >> 6, lane = t & 63;
    int rl = lane >> 3;
    int ch = lane & 7;
    int swch = ch ^ rl;
    f32x4 b0 = *(const f32x4*)(b1 + k0 + ch * 8);
    f32x4 b4 = *(const f32x4*)(b1 + k0 + ch * 8 + 4);
#pragma unroll
    for (int r = 0; r < 4; ++r) {
        int row = r * 32 + wave * 8 + rl;
        const float* src = hacc + (size_t)(row0 + row) * NHID + k0 + ch * 8;
        f32x4 v0 = *(const f32x4*)src;
        f32x4 v4 = *(const f32x4*)(src + 4);
        short8 o;
#pragma unroll
        for (int e = 0; e < 4; ++e) o[e]     = (short)f2bf(fmaxf(v0[e] + b0[e], 0.f));
#pragma unroll
        for (int e = 0; e < 4; ++e) o[4 + e] = (short)f2bf(fmaxf(v4[e] + b4[e], 0.f));
        *reinterpret_cast<short8*>(&lds[row * 64 + swch * 8]) = o;
    }
}
__device__ __forceinline__ short8 read_frag(const unsigned short* lds,
        int rowbase, int kofs, int lane) {
    int row = rowbase + (lane & 15);
    int chunkL = (kofs >> 3) + (lane >> 4);
    int sw = chunkL ^ (row & 7);
    return *reinterpret_cast<const short8*>(&lds[row * 64 + sw * 8]);
}

// ---------------------------------------------------------------------------
// GEMM1, BARRIER-FREE (R10 config — 2 blocks/CU, full register budget):
// each wave owns 64 rows x 32 cols; B frags streamed from fragment-major W1f
// (4 coalesced dwordx4/step, register double-buffered, no LDS/barriers);
// A = raw register-cached c-chunks; fold per i-group with f32 a[output-row].
// NOTE: live state ~220 VGPR (cc 128 + acc/P 64 + bufs 32) -- launch_bounds
// min-waves MUST stay at 2; (256,3) spills to scratch (R11: 1.27 GB FETCH).
// grid: bid = mb*64 + (nt + 16*s): the 8 mb-blocks of each (nt,s) group land
// on one XCD (bid%8 equal) -> shared 1MB W1f window stays L2-resident.
// ---------------------------------------------------------------------------
__global__ __launch_bounds__(256, 2) void gemm1_kernel(
        const unsigned short* __restrict__ a_tab,
        const unsigned short* __restrict__ c_tab,
        const unsigned short* __restrict__ W1f, float* __restrict__ hacc) {
    __shared__ __align__(16) unsigned short a_win[65 * 256];   // [i][row] 33 KB

    int mb = blockIdx.x >> 6;          // 0..7: 256-row slab
    int g8 = blockIdx.x & 63;
    int nt = g8 & 15;                  // 32-col slice
    int s  = g8 >> 4;                  // split 0..3
    int st0 = s * 256;
    int ngroups = (s == 3) ? 65 : 64;  // s=3 also covers i=256 (a==1) group

    int lane = threadIdx.x & 63;
    int wv   = threadIdx.x >> 6;
    int rowbase = mb * 256 + wv * 64;
    int frow = lane & 15;
    int kq = (lane >> 4) * 8;
    int r4 = (lane >> 4) * 4;
    int n16a = nt * 2, n16b = nt * 2 + 1;

    // per-lane c-chunk cache: cc[fm][q] = c_tab[rowbase+fm*16+frow][kq+32q ..+8)
    short8 cc[4][8];
#pragma unroll
    for (int fm = 0; fm < 4; ++fm)
#pragma unroll
        for (int q = 0; q < 8; ++q)
            cc[fm][q] = *reinterpret_cast<const short8*>(
                &c_tab[(size_t)(rowbase + fm * 16 + frow) * CW + kq + q * 32]);

    // a-window: a_win[i][row] = a_tab[mb*256+row][s*64+i], i in [0,65)
    {
        const unsigned short* src = a_tab + (size_t)(mb * 256 + threadIdx.x) * AW + s * 64;
        for (int i = 0; i < 65; ++i) a_win[i * 256 + threadIdx.x] = src[i];
    }
    __syncthreads();                   // the ONLY barrier

    f32x4 acc[4][2];
#pragma unroll
    for (int a = 0; a < 4; ++a)
#pragma unroll
        for (int b2 = 0; b2 < 2; ++b2) acc[a][b2] = (f32x4){0.f, 0.f, 0.f, 0.f};

    short8 bufE0, bufE1, bufE2, bufE3, bufO0, bufO1, bufO2, bufO3;

#define LOADSTEP(st, D) do { \
    const unsigned short* _p0 = W1f + ((size_t)(n16a * NSTEP_ALL + (st))) * 1024 + lane * 8; \
    const unsigned short* _p1 = W1f + ((size_t)(n16b * NSTEP_ALL + (st))) * 1024 + lane * 8; \
    D##0 = *reinterpret_cast<const short8*>(_p0); \
    D##1 = *reinterpret_cast<const short8*>(_p0 + 512); \
    D##2 = *reinterpret_cast<const short8*>(_p1); \
    D##3 = *reinterpret_cast<const short8*>(_p1 + 512); \
} while (0)
// chunks: D0 = fn0/kk0, D1 = fn0/kk1, D2 = fn1/kk0, D3 = fn1/kk1
#define MFSTEP(B, p) do { \
    _Pragma("unroll") \
    for (int fm = 0; fm < 4; ++fm) { \
        P[fm][0] = MFMA16(cc[fm][2 * (p)],     B##0, P[fm][0]); \
        P[fm][1] = MFMA16(cc[fm][2 * (p)],     B##2, P[fm][1]); \
        P[fm][0] = MFMA16(cc[fm][2 * (p) + 1], B##1, P[fm][0]); \
        P[fm][1] = MFMA16(cc[fm][2 * (p) + 1], B##3, P[fm][1]); \
    } \
} while (0)

    LOADSTEP(st0, bufE);               // prologue

    for (int g = 0; g < ngroups; ++g) {
        int stg = st0 + g * 4;
        f32x4 P[4][2];
#pragma unroll
        for (int a = 0; a < 4; ++a)
#pragma unroll
            for (int b2 = 0; b2 < 2; ++b2) P[a][b2] = (f32x4){0.f, 0.f, 0.f, 0.f};

        LOADSTEP(stg + 1, bufO);  MFSTEP(bufE, 0);
        LOADSTEP(stg + 2, bufE);  MFSTEP(bufO, 1);
        LOADSTEP(stg + 3, bufO);  MFSTEP(bufE, 2);
        LOADSTEP(stg + 4, bufE);  MFSTEP(bufO, 3);   // max st0+260=1028 < 1033 ok

        // fold i-group with a[OUTPUT row, i] in f32 (C/D rows are r4-based)
#pragma unroll
        for (int fm = 0; fm < 4; ++fm) {
            short4v a4 = *reinterpret_cast<const short4v*>(
                &a_win[g * 256 + wv * 64 + fm * 16 + r4]);
#pragma unroll
            for (int r = 0; r < 4; ++r) {
                float av = bf2f((unsigned short)a4[r]);
                acc[fm][0][r] += av * P[fm][0][r];
                acc[fm][1][r] += av * P[fm][1][r];
            }
        }
    }

    // tail (s==3): steps 1028..1032, fusion col = a(m,i); bufE holds 1028
    if (s == 3) {
#define TAILMF(B, p) do { \
    _Pragma("unroll") \
    for (int fm = 0; fm < 4; ++fm) { \
        const unsigned short* _ar = a_tab + (size_t)(rowbase + fm * 16 + frow) * AW + (p) * 64 + kq; \
        short8 t0 = *reinterpret_cast<const short8*>(_ar); \
        short8 t1 = *reinterpret_cast<const short8*>(_ar + 32); \
        acc[fm][0] = MFMA16(t0, B##0, acc[fm][0]); \
        acc[fm][1] = MFMA16(t0, B##2, acc[fm][1]); \
        acc[fm][0] = MFMA16(t1, B##1, acc[fm][0]); \
        acc[fm][1] = MFMA16(t1, B##3, acc[fm][1]); \
    } \
} while (0)
        LOADSTEP(1029, bufO);  TAILMF(bufE, 0);
        LOADSTEP(1030, bufE);  TAILMF(bufO, 1);
        LOADSTEP(1031, bufO);  TAILMF(bufE, 2);
        LOADSTEP(1032, bufE);  TAILMF(bufO, 3);
        TAILMF(bufE, 4);
    }

    // epilogue: atomic split-K accumulate into f32 hacc (in d_ws)
#pragma unroll
    for (int fm = 0; fm < 4; ++fm)
#pragma unroll
        for (int fn = 0; fn < 2; ++fn)
#pragma unroll
            for (int r = 0; r < 4; ++r) {
                int row = rowbase + fm * 16 + r4 + r;
                int col = nt * 32 + fn * 16 + frow;
                atomicAdd(&hacc[row * NHID + col], acc[fm][fn][r]);
            }
}

// ---------------------------------------------------------------------------
// GEMM2 (bias+relu+cvt fused into A-staging):
//   out = relu( bf16(relu(hacc + b1)) @ W2 + b2 ).  grid 16x4.
// ---------------------------------------------------------------------------
__global__ __launch_bounds__(256) void gemm2_kernel(
        const float* __restrict__ hacc, const float* __restrict__ b1,
        const unsigned short* __restrict__ W2t,
        const float* __restrict__ b2, float* __restrict__ out) {
    __shared__ unsigned short A_s[128 * 64];
    __shared__ unsigned short B_s[128 * 64];
    int m0 = (blockIdx.x >> 2) * 128;
    int n0 = (blockIdx.x & 3) * 128;
    int lane = threadIdx.x & 63;
    int wv = threadIdx.x >> 6;
    int wm = (wv >> 1) * 64;
    int wn = (wv & 1) * 64;

    f32x4 acc[4][4];
#pragma unroll
    for (int a = 0; a < 4; ++a)
#pragma unroll
        for (int b = 0; b < 4; ++b) acc[a][b] = (f32x4){0.f, 0.f, 0.f, 0.f};

    for (int st = 0; st < 8; ++st) {
        int kbase = st * 64;
        __syncthreads();
        stage_tile128(W2t, n0, kbase, NHID, B_s);   // async loads in flight...
        stage_h_tile(hacc, b1, m0, kbase, A_s);     // ...VALU staging overlaps
        __syncthreads();
#pragma unroll
        for (int kk = 0; kk < 2; ++kk) {
            short8 aF[4], bF[4];
#pragma unroll
            for (int fm = 0; fm < 4; ++fm) aF[fm] = read_frag(A_s, wm + fm * 16, kk * 32, lane);
#pragma unroll
            for (int fn = 0; fn < 4; ++fn) bF[fn] = read_frag(B_s, wn + fn * 16, kk * 32, lane);
#pragma unroll
            for (int fm = 0; fm < 4; ++fm)
#pragma unroll
                for (int fn = 0; fn < 4; ++fn)
                    acc[fm][fn] = __builtin_amdgcn_mfma_f32_16x16x32_bf16(
                        aF[fm], bF[fn], acc[fm][fn], 0, 0, 0);
        }
    }
    int cl = lane & 15;
    int r4 = (lane >> 4) * 4;
#pragma unroll
    for (int fm = 0; fm < 4; ++fm)
#pragma unroll
        for (int fn = 0; fn < 4; ++fn)
#pragma unroll
            for (int r = 0; r < 4; ++r) {
                int row = m0 + wm + fm * 16 + r4 + r;
                int col = n0 + wn + fn * 16 + cl;
                float x = acc[fm][fn][r] + b2[col];
                out[row * NHID + col] = fmaxf(x, 0.f);
            }
}

extern "C" void kernel_launch(void* const* d_in, const int* in_sizes, int n_in,
                              void* d_out, int out_size, void* d_ws, size_t ws_size,
                              hipStream_t stream) {
    const float* inp1 = (const float*)d_in[0];
    const float* inp2 = (const float*)d_in[1];
    const float* W1   = (const float*)d_in[2];
    const float* b1   = (const float*)d_in[3];
    const float* W2   = (const float*)d_in[4];
    const float* b2   = (const float*)d_in[5];
    float* out = (float*)d_out;

    // workspace layout (~75 MB)
    size_t off = 0;
    auto alloc = [&](size_t bytes) {
        void* p = (char*)d_ws + off;
        off += (bytes + 255) & ~(size_t)255;
        return p;
    };
    unsigned short* W1f   = (unsigned short*)alloc((size_t)32 * NSTEP_ALL * 1024 * 2);
    unsigned short* W2t   = (unsigned short*)alloc((size_t)NHID * NHID * 2);
    float*          hacc  = (float*)alloc((size_t)BATCH * NHID * 4);
    unsigned short* a_tab = (unsigned short*)alloc((size_t)BATCH * AW * 2);
    unsigned short* c_tab = (unsigned short*)alloc((size_t)BATCH * CW * 2);
    (void)ws_size; (void)in_sizes; (void)n_in; (void)out_size;

    hipMemsetAsync(hacc, 0, (size_t)BATCH * NHID * 4, stream);

    prep_kernel<<<8264 + 64 + 64, 256, 0, stream>>>(inp1, inp2, W1, W2,
                                                    W1f, W2t, a_tab, c_tab);

    gemm1_kernel<<<512, 256, 0, stream>>>(a_tab, c_tab, W1f, hacc);
    gemm2_kernel<<<64, 256, 0, stream>>>(hacc, b1, W2t, b2, out);
}

// Round 14
// 180.647 us; speedup vs baseline: 2.5839x; 1.0164x over previous
//
#include <hip/hip_runtime.h>
#include <hip/hip_bf16.h>
#include <stdint.h>

// Shapes (fixed by the problem)
#define BATCH 2048
#define NHID  512
#define KMAIN 65792          // 257*256  (k = i*256 + j, j<256; i=0..256)
#define NSTEP_ALL 1033       // 1028 main steps + 5 tail steps (j=256 column)
#define AW 320               // a_tab row width (257 vals: a[256]=1.0; zeros to 320)
#define CW 256               // c_tab row width

typedef __attribute__((ext_vector_type(8))) short short8;
typedef __attribute__((ext_vector_type(4))) short short4v;
typedef __attribute__((ext_vector_type(4))) float f32x4;

#define AS1 __attribute__((address_space(1)))
#define AS3 __attribute__((address_space(3)))

__device__ __forceinline__ unsigned short f2bf(float f) {
    union { float f; unsigned int u; } v; v.f = f;
    unsigned int r = v.u + 0x7FFFu + ((v.u >> 16) & 1u);
    return (unsigned short)(r >> 16);
}
__device__ __forceinline__ float bf2f(unsigned short u) {
    union { unsigned int i; float f; } v; v.i = ((unsigned int)u) << 16;
    return v.f;
}
__device__ __forceinline__ f32x4 MFMA16(short8 a, short8 b, f32x4 c) {
    return __builtin_amdgcn_mfma_f32_16x16x32_bf16(a, b, c, 0, 0, 0);
}

// W1 source row for permuted k (or -1 for zero-pad)
__device__ __forceinline__ int w1_src_row(int k) {
    if (k < KMAIN) return (k >> 8) * 257 + (k & 255);   // i*257 + j
    int i = k - KMAIN;
    return (i < 257) ? (i * 257 + 256) : -1;             // (i, j=256) column
}

// ---------------------------------------------------------------------------
// Merged prep: W1f (FRAGMENT-MAJOR permuted W1), W2t (row-major transpose),
// a_tab [2048][320] bf16, c_tab [2048][256] bf16.  One launch.
// W1f layout: chunk(n16, st, kk, lane) at ((n16*1033+st)*2+kk)*512 + lane*8,
// elems e: value = W1perm[st*64 + kk*32 + (lane>>4)*8 + e][n16*16 + (lane&15)].
// ---------------------------------------------------------------------------
__global__ __launch_bounds__(256) void prep_kernel(
        const float* __restrict__ inp1, const float* __restrict__ inp2,
        const float* __restrict__ W1, const float* __restrict__ W2,
        unsigned short* __restrict__ W1f, unsigned short* __restrict__ W2t,
        unsigned short* __restrict__ a_tab, unsigned short* __restrict__ c_tab) {
    __shared__ float T[64][65];
    int b = blockIdx.x;
    int t = threadIdx.x;

    if (b < 8264) {
        // ---- W1f tile: 64 k x 64 n ----
        int kt = b % 1033, nt = b / 1033;
        int k0 = kt * 64, n0 = nt * 64;
        int nn = t & 63, kk0 = t >> 6;
#pragma unroll
        for (int it = 0; it < 16; ++it) {
            int kk = it * 4 + kk0;
            int row = w1_src_row(k0 + kk);
            T[kk][nn] = (row >= 0) ? W1[(long)row * NHID + n0 + nn] : 0.f;
        }
        __syncthreads();
#pragma unroll
        for (int it = 0; it < 2; ++it) {
            int id = it * 256 + t;
            int n16l = id >> 7;            // 0..3
            int kk   = (id >> 6) & 1;
            int lw   = id & 63;
            short8 o;
#pragma unroll
            for (int e = 0; e < 8; ++e)
                o[e] = (short)f2bf(T[kk * 32 + (lw >> 4) * 8 + e][n16l * 16 + (lw & 15)]);
            size_t off = ((size_t)(((n0 >> 4) + n16l) * NSTEP_ALL + kt) * 2 + kk) * 512
                         + (size_t)lw * 8;
            *reinterpret_cast<short8*>(&W1f[off]) = o;
        }
    } else if (b < 8264 + 64) {
        // ---- W2t: plain transpose+cvt (row-major, gemm2's LDS path) ----
        int bb = b - 8264;
        int kt = bb & 7, nt = bb >> 3;
        int k0 = kt * 64, n0 = nt * 64;
        int nn = t & 63, kk0 = t >> 6;
#pragma unroll
        for (int it = 0; it < 16; ++it) {
            int kk = it * 4 + kk0;
            T[kk][nn] = W2[(long)(k0 + kk) * NHID + n0 + nn];
        }
        __syncthreads();
#pragma unroll
        for (int it = 0; it < 2; ++it) {
            int idx = it * 256 + t;
            int nl = idx >> 3, ch = idx & 7;
            short8 o;
#pragma unroll
            for (int e = 0; e < 8; ++e) o[e] = (short)f2bf(T[ch * 8 + e][nl]);
            *reinterpret_cast<short8*>(&W2t[(long)(n0 + nl) * NHID + k0 + ch * 8]) = o;
        }
    } else {
        int r0 = (b - 8328) * 32;
        for (int idx = t; idx < 32 * (AW / 8); idx += 256) {
            int r = idx / 40, ch = idx - r * 40;
            int m = r0 + r;
            short8 o;
#pragma unroll
            for (int e = 0; e < 8; ++e) {
                int i = ch * 8 + e;
                float v = (i < 256) ? inp1[m * 256 + i] : (i == 256 ? 1.0f : 0.0f);
                o[e] = (short)f2bf(v);
            }
            *reinterpret_cast<short8*>(&a_tab[m * AW + ch * 8]) = o;
        }
        for (int idx = t; idx < 32 * (CW / 8); idx += 256) {
            int r = idx >> 5, ch = idx & 31;
            int m = r0 + r;
            short8 o;
#pragma unroll
            for (int e = 0; e < 8; ++e) o[e] = (short)f2bf(inp2[m * 256 + ch * 8 + e]);
            *reinterpret_cast<short8*>(&c_tab[m * CW + ch * 8]) = o;
        }
    }
}

// ---------------------------------------------------------------------------
// Staging helpers (gemm2)
// ---------------------------------------------------------------------------
__device__ __forceinline__ void stage_tile128(const unsigned short* __restrict__ g,
        long row0, long k0, long ld, unsigned short* lds) {
    int t = threadIdx.x;
    int wave = t >> 6, lane = t & 63;
    int rl = lane >> 3;
    int ch = (lane & 7) ^ rl;
    const unsigned short* src0 = g + (row0 + wave * 8 + rl) * ld + k0 + ch * 8;
#pragma unroll
    for (int r = 0; r < 4; ++r) {
        const unsigned short* src = src0 + (long)r * 32 * ld;
        unsigned short* dst = lds + (r * 32 + wave * 8) * 64;
        __builtin_amdgcn_global_load_lds((const AS1 unsigned int*)src,
                                         (AS3 unsigned int*)dst, 16, 0, 0);
    }
}
// Fused h-staging: lds tile = bf16(relu(hacc + b1)), swizzled like stage_tile128
__device__ __forceinline__ void stage_h_tile(const float* __restrict__ hacc,
        const float* __restrict__ b1, int row0, int k0, unsigned short* lds) {
    int t = threadIdx.x;
    int wave = t >> 6, lane = t & 63;
    int rl = lane >> 3;
    int ch = lane & 7;
    int swch = ch ^ rl;
    f32x4 b0 = *(const f32x4*)(b1 + k0 + ch * 8);
    f32x4 b4 = *(const f32x4*)(b1 + k0 + ch * 8 + 4);
#pragma unroll
    for (int r = 0; r < 4; ++r) {
        int row = r * 32 + wave * 8 + rl;
        const float* src = hacc + (size_t)(row0 + row) * NHID + k0 + ch * 8;
        f32x4 v0 = *(const f32x4*)src;
        f32x4 v4 = *(const f32x4*)(src + 4);
        short8 o;
#pragma unroll
        for (int e = 0; e < 4; ++e) o[e]     = (short)f2bf(fmaxf(v0[e] + b0[e], 0.f));
#pragma unroll
        for (int e = 0; e < 4; ++e) o[4 + e] = (short)f2bf(fmaxf(v4[e] + b4[e], 0.f));
        *reinterpret_cast<short8*>(&lds[row * 64 + swch * 8]) = o;
    }
}
__device__ __forceinline__ short8 read_frag(const unsigned short* lds,
        int rowbase, int kofs, int lane) {
    int row = rowbase + (lane & 15);
    int chunkL = (kofs >> 3) + (lane >> 4);
    int sw = chunkL ^ (row & 7);
    return *reinterpret_cast<const short8*>(&lds[row * 64 + sw * 8]);
}

// ---------------------------------------------------------------------------
// GEMM1, LDS-SHARED B:  h[m,n] = sum_i a[m,i] * P_i[m,n].
// Kills the 4x within-block B redundancy (R12 was at the per-CU L2 delivery
// ceiling: 2.17 GB -> 542 MB).  Per phase (= one i-group = 4 K-steps):
//   STAGE next phase's 16 KB into ring[cur^1]  (wave wv stages step wv)
//   compute 4 steps x {4 LDS chunk reads + 16 MFMA} from ring[cur]
//   fold with f32 a[output-row]
//   __syncthreads()   <- the ONE sync point: compiler-modeled fence+drain
//                        (R13's hand-rolled vmcnt+raw-barrier ledger raced
//                         across graph replays -- m152 failure mode)
// A-operand = register-cached c-chunks.
// grid: bid = mb*64 + (nt + 16*s); 8 mb-blocks of each (nt,s) share an XCD.
// 512 blocks = 2/CU (anti-phased pairs hide barrier stalls).
// ---------------------------------------------------------------------------
__global__ __launch_bounds__(256, 2) void gemm1_kernel(
        const unsigned short* __restrict__ a_tab,
        const unsigned short* __restrict__ c_tab,
        const unsigned short* __restrict__ W1f, float* __restrict__ hacc) {
    __shared__ __align__(16) unsigned short B_s[2][8192];      // 2 x 16 KB ring
    __shared__ __align__(16) unsigned short a_win[65 * 256];   // [i][row] 33 KB

    int mb = blockIdx.x >> 6;          // 0..7: 256-row slab
    int g8 = blockIdx.x & 63;
    int nt = g8 & 15;                  // 32-col slice
    int s  = g8 >> 4;                  // split 0..3
    int st0 = s * 256;
    int ngroups = (s == 3) ? 65 : 64;  // s=3 also covers i=256 (a==1) group

    int lane = threadIdx.x & 63;
    int wv   = threadIdx.x >> 6;
    int rowbase = mb * 256 + wv * 64;
    int frow = lane & 15;
    int kq = (lane >> 4) * 8;
    int r4 = (lane >> 4) * 4;
    int n16a = nt * 2, n16b = nt * 2 + 1;

    // per-lane c-chunk cache: cc[fm][q] = c_tab[rowbase+fm*16+frow][kq+32q ..+8)
    short8 cc[4][8];
#pragma unroll
    for (int fm = 0; fm < 4; ++fm)
#pragma unroll
        for (int q = 0; q < 8; ++q)
            cc[fm][q] = *reinterpret_cast<const short8*>(
                &c_tab[(size_t)(rowbase + fm * 16 + frow) * CW + kq + q * 32]);

    // a-window: a_win[i][row] = a_tab[mb*256+row][s*64+i], i in [0,65)
    {
        const unsigned short* src = a_tab + (size_t)(mb * 256 + threadIdx.x) * AW + s * 64;
        for (int i = 0; i < 65; ++i) a_win[i * 256 + threadIdx.x] = src[i];
    }

    // stage one phase: wave wv stages step (stg+wv) = chunks 4wv..4wv+3
#define STAGE_PHASE(stg, buf) do { \
    _Pragma("unroll") \
    for (int j = 0; j < 4; ++j) { \
        int c = wv * 4 + j;                       /* chunk 0..15 */ \
        int fnsel = j >> 1, kkc = j & 1; \
        int n16 = fnsel ? n16b : n16a; \
        const unsigned short* src = W1f + \
            ((size_t)(n16 * NSTEP_ALL + (stg) + wv) * 2 + kkc) * 512 + lane * 8; \
        __builtin_amdgcn_global_load_lds((const AS1 unsigned int*)src, \
                                         (AS3 unsigned int*)((buf) + c * 512), 16, 0, 0); \
    } \
} while (0)

    STAGE_PHASE(st0, &B_s[0][0]);
    __syncthreads();                   // publishes a_win + drains phase-0 staging

    f32x4 acc[4][2];
#pragma unroll
    for (int a = 0; a < 4; ++a)
#pragma unroll
        for (int b2 = 0; b2 < 2; ++b2) acc[a][b2] = (f32x4){0.f, 0.f, 0.f, 0.f};

    int cur = 0;
    for (int g = 0; g < ngroups; ++g) {
        int stg = st0 + g * 4;
        if (g + 1 < ngroups)
            STAGE_PHASE(stg + 4, &B_s[cur ^ 1][0]);   // issue-early
        __builtin_amdgcn_sched_barrier(0);            // pin staging before compute

        f32x4 P[4][2];
#pragma unroll
        for (int a = 0; a < 4; ++a)
#pragma unroll
            for (int b2 = 0; b2 < 2; ++b2) P[a][b2] = (f32x4){0.f, 0.f, 0.f, 0.f};

        const unsigned short* bb = &B_s[cur][0];
#pragma unroll
        for (int p = 0; p < 4; ++p) {
            // chunk c = p*4 + fn*2 + kk, each 512 shorts; lane reads its 16 B
            short8 b00 = *reinterpret_cast<const short8*>(&bb[(p * 4 + 0) * 512 + lane * 8]);
            short8 b01 = *reinterpret_cast<const short8*>(&bb[(p * 4 + 1) * 512 + lane * 8]);
            short8 b10 = *reinterpret_cast<const short8*>(&bb[(p * 4 + 2) * 512 + lane * 8]);
            short8 b11 = *reinterpret_cast<const short8*>(&bb[(p * 4 + 3) * 512 + lane * 8]);
#pragma unroll
            for (int fm = 0; fm < 4; ++fm) {
                P[fm][0] = MFMA16(cc[fm][2 * p],     b00, P[fm][0]);
                P[fm][1] = MFMA16(cc[fm][2 * p],     b10, P[fm][1]);
                P[fm][0] = MFMA16(cc[fm][2 * p + 1], b01, P[fm][0]);
                P[fm][1] = MFMA16(cc[fm][2 * p + 1], b11, P[fm][1]);
            }
        }

        // fold i-group with a[OUTPUT row, i] in f32 (C/D rows are r4-based)
#pragma unroll
        for (int fm = 0; fm < 4; ++fm) {
            short4v a4 = *reinterpret_cast<const short4v*>(
                &a_win[g * 256 + wv * 64 + fm * 16 + r4]);
#pragma unroll
            for (int r = 0; r < 4; ++r) {
                float av = bf2f((unsigned short)a4[r]);
                acc[fm][0][r] += av * P[fm][0][r];
                acc[fm][1][r] += av * P[fm][1][r];
            }
        }

        __syncthreads();               // full fence+drain: next buffer ready,
        cur ^= 1;                      // old buffer safe to overwrite
    }

    // tail (s==3): steps 1028..1032, fusion col = a(m,i); register B path
    if (s == 3) {
        short8 bufE0, bufE1, bufE2, bufE3, bufO0, bufO1, bufO2, bufO3;
#define LOADSTEP(st, D) do { \
    const unsigned short* _p0 = W1f + ((size_t)(n16a * NSTEP_ALL + (st))) * 1024 + lane * 8; \
    const unsigned short* _p1 = W1f + ((size_t)(n16b * NSTEP_ALL + (st))) * 1024 + lane * 8; \
    D##0 = *reinterpret_cast<const short8*>(_p0); \
    D##1 = *reinterpret_cast<const short8*>(_p0 + 512); \
    D##2 = *reinterpret_cast<const short8*>(_p1); \
    D##3 = *reinterpret_cast<const short8*>(_p1 + 512); \
} while (0)
#define TAILMF(B, p) do { \
    _Pragma("unroll") \
    for (int fm = 0; fm < 4; ++fm) { \
        const unsigned short* _ar = a_tab + (size_t)(rowbase + fm * 16 + frow) * AW + (p) * 64 + kq; \
        short8 t0 = *reinterpret_cast<const short8*>(_ar); \
        short8 t1 = *reinterpret_cast<const short8*>(_ar + 32); \
        acc[fm][0] = MFMA16(t0, B##0, acc[fm][0]); \
        acc[fm][1] = MFMA16(t0, B##2, acc[fm][1]); \
        acc[fm][0] = MFMA16(t1, B##1, acc[fm][0]); \
        acc[fm][1] = MFMA16(t1, B##3, acc[fm][1]); \
    } \
} while (0)
        LOADSTEP(1028, bufE);
        LOADSTEP(1029, bufO);  TAILMF(bufE, 0);
        LOADSTEP(1030, bufE);  TAILMF(bufO, 1);
        LOADSTEP(1031, bufO);  TAILMF(bufE, 2);
        LOADSTEP(1032, bufE);  TAILMF(bufO, 3);
        TAILMF(bufE, 4);
    }

    // epilogue: atomic split-K accumulate into f32 hacc (in d_ws)
#pragma unroll
    for (int fm = 0; fm < 4; ++fm)
#pragma unroll
        for (int fn = 0; fn < 2; ++fn)
#pragma unroll
            for (int r = 0; r < 4; ++r) {
                int row = rowbase + fm * 16 + r4 + r;
                int col = nt * 32 + fn * 16 + frow;
                atomicAdd(&hacc[row * NHID + col], acc[fm][fn][r]);
            }
}

// ---------------------------------------------------------------------------
// GEMM2 (bias+relu+cvt fused into A-staging):
//   out = relu( bf16(relu(hacc + b1)) @ W2 + b2 ).  grid 16x4.
// ---------------------------------------------------------------------------
__global__ __launch_bounds__(256) void gemm2_kernel(
        const float* __restrict__ hacc, const float* __restrict__ b1,
        const unsigned short* __restrict__ W2t,
        const float* __restrict__ b2, float* __restrict__ out) {
    __shared__ unsigned short A_s[128 * 64];
    __shared__ unsigned short B_s[128 * 64];
    int m0 = (blockIdx.x >> 2) * 128;
    int n0 = (blockIdx.x & 3) * 128;
    int lane = threadIdx.x & 63;
    int wv = threadIdx.x >> 6;
    int wm = (wv >> 1) * 64;
    int wn = (wv & 1) * 64;

    f32x4 acc[4][4];
#pragma unroll
    for (int a = 0; a < 4; ++a)
#pragma unroll
        for (int b = 0; b < 4; ++b) acc[a][b] = (f32x4){0.f, 0.f, 0.f, 0.f};

    for (int st = 0; st < 8; ++st) {
        int kbase = st * 64;
        __syncthreads();
        stage_tile128(W2t, n0, kbase, NHID, B_s);   // async loads in flight...
        stage_h_tile(hacc, b1, m0, kbase, A_s);     // ...VALU staging overlaps
        __syncthreads();
#pragma unroll
        for (int kk = 0; kk < 2; ++kk) {
            short8 aF[4], bF[4];
#pragma unroll
            for (int fm = 0; fm < 4; ++fm) aF[fm] = read_frag(A_s, wm + fm * 16, kk * 32, lane);
#pragma unroll
            for (int fn = 0; fn < 4; ++fn) bF[fn] = read_frag(B_s, wn + fn * 16, kk * 32, lane);
#pragma unroll
            for (int fm = 0; fm < 4; ++fm)
#pragma unroll
                for (int fn = 0; fn < 4; ++fn)
                    acc[fm][fn] = __builtin_amdgcn_mfma_f32_16x16x32_bf16(
                        aF[fm], bF[fn], acc[fm][fn], 0, 0, 0);
        }
    }
    int cl = lane & 15;
    int r4 = (lane >> 4) * 4;
#pragma unroll
    for (int fm = 0; fm < 4; ++fm)
#pragma unroll
        for (int fn = 0; fn < 4; ++fn)
#pragma unroll
            for (int r = 0; r < 4; ++r) {
                int row = m0 + wm + fm * 16 + r4 + r;
                int col = n0 + wn + fn * 16 + cl;
                float x = acc[fm][fn][r] + b2[col];
                out[row * NHID + col] = fmaxf(x, 0.f);
            }
}

extern "C" void kernel_launch(void* const* d_in, const int* in_sizes, int n_in,
                              void* d_out, int out_size, void* d_ws, size_t ws_size,
                              hipStream_t stream) {
    const float* inp1 = (const float*)d_in[0];
    const float* inp2 = (const float*)d_in[1];
    const float* W1   = (const float*)d_in[2];
    const float* b1   = (const float*)d_in[3];
    const float* W2   = (const float*)d_in[4];
    const float* b2   = (const float*)d_in[5];
    float* out = (float*)d_out;

    // workspace layout (~75 MB)
    size_t off = 0;
    auto alloc = [&](size_t bytes) {
        void* p = (char*)d_ws + off;
        off += (bytes + 255) & ~(size_t)255;
        return p;
    };
    unsigned short* W1f   = (unsigned short*)alloc((size_t)32 * NSTEP_ALL * 1024 * 2);
    unsigned short* W2t   = (unsigned short*)alloc((size_t)NHID * NHID * 2);
    float*          hacc  = (float*)alloc((size_t)BATCH * NHID * 4);
    unsigned short* a_tab = (unsigned short*)alloc((size_t)BATCH * AW * 2);
    unsigned short* c_tab = (unsigned short*)alloc((size_t)BATCH * CW * 2);
    (void)ws_size; (void)in_sizes; (void)n_in; (void)out_size;

    hipMemsetAsync(hacc, 0, (size_t)BATCH * NHID * 4, stream);

    prep_kernel<<<8264 + 64 + 64, 256, 0, stream>>>(inp1, inp2, W1, W2,
                                                    W1f, W2t, a_tab, c_tab);

    gemm1_kernel<<<512, 256, 0, stream>>>(a_tab, c_tab, W1f, hacc);
    gemm2_kernel<<<64, 256, 0, stream>>>(hacc, b1, W2t, b2, out);
}